// Round 4
// baseline (17803.946 us; speedup 1.0000x reference)
//
#include <hip/hip_runtime.h>
#include <math.h>

typedef __bf16 bf16;
typedef __bf16 bf16x8 __attribute__((ext_vector_type(8)));
typedef float f32x4 __attribute__((ext_vector_type(4)));
typedef int i32x4 __attribute__((ext_vector_type(4)));
typedef unsigned int u32;
typedef unsigned short u16;

#define TT 1024
#define BB 32
#define HH 512

// ---- workspace layout (bytes) ----
#define OFF_CTL   0ull                     // int abort@0, prog1[2]@1..2
#define OFF_WBT   4096ull                  // W_out^T bf16 [1024][1024] = 2 MB
#define OFF_FRAG  (OFF_WBT + 2097152ull)   // 3 arrays x 8MB: Wi-hi, Wh-hi, Wh-lo
#define FRAG_B    8388608ull
#define OFF_PL    (OFF_FRAG + 3ull*FRAG_B) // packed planes: 4 grp x 16 slot x 64KB
#define PL_SLOT   65536ull
#define PL_GRP    (16ull*PL_SLOT)
#define OFF_H1    (OFF_PL + 4ull*PL_GRP)   // layer-1 h as bf16: [2][1025*32*512]
#define H1_ELEM   ((size_t)(TT+1)*BB*HH)
// total ~= 4K + 2M + 24M + 4M + 67.2M ~= 97.3 MB (< 141 MB proven in round 1)

// packed word: low16 = bf16 hi(h), high16 = bf16 lo(h) with LSB = lap parity
__global__ void k_setup(const float* __restrict__ h0, const float* __restrict__ wout,
                        const float* __restrict__ Wi_f, const float* __restrict__ Wh_f,
                        const float* __restrict__ Wi_b, const float* __restrict__ Wh_b,
                        unsigned char* __restrict__ ws) {
  const u32 N0 = 1048576, N1 = 1048576, N3 = 2097152, N4 = 2097152, N5 = 16;
  const u32 total = N0 + N1 + N3 + N4 + N5;
  for (u32 i = blockIdx.x*blockDim.x + threadIdx.x; i < total; i += gridDim.x*blockDim.x) {
    if (i < N0) {
      u32 jj = i >> 10, kk = i & 1023u;
      ((bf16*)(ws + OFF_WBT))[(size_t)jj*1024 + kk] = (bf16)wout[(size_t)kk*1024 + jj];
    } else if (i < N0 + N1) {
      u32 t = i - N0;
      u32 g = t >> 18, rem = t & 262143u;
      u32 slot = rem >> 14, r = rem & 16383u;
      u32 word = 0x00010000u;                    // parity-1 poison
      if (slot == 15) {                          // h(-1) = h0, parity 1
        u32 b = r >> 9, u = r & 511u, l = g >> 1;
        float v = h0[((size_t)l*BB + b)*HH + u];
        bf16 hi = (bf16)v;
        bf16 lo = (bf16)(v - (float)hi);
        u16 lob = (u16)((__builtin_bit_cast(u16, lo) & 0xFFFEu) | 1u);
        word = (u32)__builtin_bit_cast(u16, hi) | ((u32)lob << 16);
      }
      *(u32*)(ws + OFF_PL + (size_t)g*PL_GRP + (size_t)slot*PL_SLOT + (size_t)r*4) = word;
    } else if (i < N0 + N1 + N3 + N4) {
      u32 t = i - N0 - N1;
      int isWh = (t >= N3);
      if (isWh) t -= N3;
      u32 e2 = t & 3u, lane = (t>>2)&63u, j = (t>>8)&1u, nt = (t>>9)&3u;
      u32 q = (t>>11)&7u, w2 = (t>>14)&31u, g = (t>>19)&3u;
      u32 l = g >> 1, d = g & 1;
      u32 lrow = lane & 15u;
      u32 cc = nt*16 + lrow;
      u32 unit = cc >> 2, gate = cc & 3u;
      u32 J = gate*512 + w2*16 + unit;
      u32 k = q*64 + j*32 + (lane>>4)*8 + e2*2;
      const float* src = isWh ? ((d ? Wh_b : Wh_f) + (size_t)l*HH*2048)
                              : ((d ? Wi_b : Wi_f) + (size_t)l*HH*2048);
      float v0 = src[(size_t)k*2048 + J];
      float v1 = src[(size_t)(k+1)*2048 + J];
      size_t fo = (((((((size_t)g*32+w2)*8+q)*4+nt)*2+j)*64+lane)*8 + e2*2);
      if (!isWh) {
        u32 word = (u32)__builtin_bit_cast(u16,(bf16)v0) | ((u32)__builtin_bit_cast(u16,(bf16)v1) << 16);
        *(u32*)(ws + OFF_FRAG + fo*2) = word;
      } else {
        bf16 h0b = (bf16)v0, h1b = (bf16)v1;
        bf16 l0b = (bf16)(v0 - (float)h0b), l1b = (bf16)(v1 - (float)h1b);
        *(u32*)(ws + OFF_FRAG + FRAG_B + fo*2) =
          (u32)__builtin_bit_cast(u16,h0b) | ((u32)__builtin_bit_cast(u16,h1b) << 16);
        *(u32*)(ws + OFF_FRAG + 2ull*FRAG_B + fo*2) =
          (u32)__builtin_bit_cast(u16,l0b) | ((u32)__builtin_bit_cast(u16,l1b) << 16);
      }
    } else {
      u32 t = i - (N0+N1+N3+N4);
      int* pc = (int*)(ws + OFF_CTL);
      if (t == 0) pc[0] = 0;                 // abort
      else if (t <= 2) pc[t] = -1;           // prog1[2]
      else pc[t] = 0;
    }
  }
}

#define LD16(dst, p) asm volatile("global_load_dwordx4 %0, %1, off sc0 sc1" : "=v"(dst) : "v"(p) : "memory")
#define ST4(p, v)    asm volatile("global_store_dword %0, %1, off sc0 sc1" :: "v"(p), "v"(v) : "memory")
#define WAIT0() do { asm volatile("s_waitcnt vmcnt(0)" ::: "memory"); __builtin_amdgcn_sched_barrier(0); } while (0)

__launch_bounds__(512)
__global__ void k_rnn(const float* __restrict__ x, const float* __restrict__ c0,
                      const float* __restrict__ b_f, const float* __restrict__ b_b,
                      unsigned char* __restrict__ ws) {
  __shared__ float gb[4][32][68];
  __shared__ int sdead;

  const int bid = blockIdx.x;
  if (bid & 1) return;                 // participants: 128 blocks, one XCD class per group
  const int g = (bid >> 1) & 3;        // layer*2 + dir
  const int w = bid >> 3;              // 0..31, owns units w*16..w*16+15
  const int l = g >> 1, d = g & 1;
  const int tid = threadIdx.x;
  const int lane = tid & 63;
  const int q = tid >> 6;              // wave 0..7, owns k = q*64..q*64+63
  const int lrow = lane & 15;
  const int ksub = (lane >> 4) * 8;

  int* ctl    = (int*)(ws + OFF_CTL);
  int* abortf = ctl;
  int* prog1  = ctl + 1;

  if (tid == 0) sdead = 0;

  // ---- pre-packed weight fragments (coalesced dwordx4 loads) ----
  bf16x8 BWi[4][2], BWh[4][2], BWlo[4][2];
#pragma unroll
  for (int nt = 0; nt < 4; ++nt)
#pragma unroll
    for (int j = 0; j < 2; ++j) {
      size_t fo = (((((((size_t)g*32+w)*8+q)*4+nt)*2+j)*64+lane)*8) * 2;
      BWi[nt][j]  = *(const bf16x8*)(ws + OFF_FRAG + fo);
      BWh[nt][j]  = *(const bf16x8*)(ws + OFF_FRAG + FRAG_B + fo);
      BWlo[nt][j] = *(const bf16x8*)(ws + OFF_FRAG + 2ull*FRAG_B + fo);
    }

  const int bthr = tid >> 4, uthr = tid & 15;
  const int hu = w*16 + uthr;
  float cst = c0[((size_t)l*BB + bthr)*HH + hu];
  const float* bias = (d ? b_b : b_f) + (size_t)l*2048;
  const float bgi = bias[hu], bgf = bias[512+hu], bgg = bias[1024+hu], bgo = bias[1536+hu];

  unsigned char* plMain = ws + OFF_PL + (size_t)g*PL_GRP;     // own plane
  unsigned char* plIn   = ws + OFF_PL + (size_t)d*PL_GRP;     // layer-0 plane (x for layer 1)
  bf16* H1p = (bf16*)(ws + OFF_H1) + (size_t)d*H1_ELEM;

  u32 ao[2][2];
#pragma unroll
  for (int j = 0; j < 2; ++j)
#pragma unroll
    for (int mt = 0; mt < 2; ++mt)
      ao[j][mt] = (u32)((((mt*16 + lrow)*512) + q*64 + j*32 + ksub) * 4);

  __syncthreads();

  // ---- x prefetch (pipelined one tick ahead) ----
  float4 xr[8];
  i32x4  xm[4][2];
  if (l == 0) {
    int t0i = d ? (TT-1) : 0;
#pragma unroll
    for (int p = 0; p < 4; ++p) {
      int j = p >> 1, mt = p & 1;
      const float* px = x + (((size_t)(mt*16+lrow))*TT + t0i)*512 + q*64 + j*32 + ksub;
      xr[p*2]   = *(const float4*)px;
      xr[p*2+1] = *(const float4*)(px + 4);
    }
  } else {
#pragma unroll
    for (int p = 0; p < 4; ++p) {
      int j = p >> 1, mt = p & 1;
      const unsigned char* pp = plIn + ao[j][mt];   // slot 0
      LD16(xm[p][0], pp);
      LD16(xm[p][1], pp + 16);
    }
  }

  int prog_cache = -1000000;
  int dead = 0;

  for (int s = 0; s < TT; ++s) {
    const int slot_w = s & 15;
    const u32 par_w = (u32)((s >> 4) & 1);
    const u32 par_r = (u32)(((s - 1) >> 4) & 1);
    const unsigned char* slotR = plMain + (size_t)((s - 1) & 15)*PL_SLOT;

    // ---- own-h poll: the payload IS the flag (per-word lap parity) ----
    i32x4 hw[4][2];
    {
      const u32 expw = par_r << 16;
      int pit = 0;
      while (true) {
#pragma unroll
        for (int p = 0; p < 4; ++p) {
          int j = p >> 1, mt = p & 1;
          LD16(hw[p][0], slotR + ao[j][mt]);
          LD16(hw[p][1], slotR + ao[j][mt] + 16);
        }
        WAIT0();
        if (dead) break;
        u32 m = 0;
#pragma unroll
        for (int p = 0; p < 4; ++p)
#pragma unroll
          for (int hh = 0; hh < 2; ++hh)
#pragma unroll
            for (int e = 0; e < 4; ++e)
              m |= ((u32)hw[p][hh][e]) ^ expw;
        if (__all((int)(((m >> 16) & 1u) == 0u))) break;
        ++pit;
        if (pit > 64) __builtin_amdgcn_s_sleep(1);
        if ((pit & 255) == 0) {
          if (sdead || __hip_atomic_load(abortf, __ATOMIC_RELAXED, __HIP_MEMORY_SCOPE_AGENT)) dead = 1;
          if (pit > (1 << 20)) {
            __hip_atomic_store(abortf, 1, __ATOMIC_RELAXED, __HIP_MEMORY_SCOPE_AGENT);
            sdead = 1; dead = 1;
          }
        }
      }
    }

    f32x4 acc[2][4];
#pragma unroll
    for (int mt = 0; mt < 2; ++mt)
#pragma unroll
      for (int nt = 0; nt < 4; ++nt) acc[mt][nt] = (f32x4){0.f, 0.f, 0.f, 0.f};

    // ---- x phase ----
    if (l == 0) {
#pragma unroll
      for (int p = 0; p < 4; ++p) {
        int j = p >> 1, mt = p & 1;
        float4 a = xr[p*2], b4 = xr[p*2+1];
        bf16x8 ax = { (bf16)a.x,(bf16)a.y,(bf16)a.z,(bf16)a.w,
                      (bf16)b4.x,(bf16)b4.y,(bf16)b4.z,(bf16)b4.w };
#pragma unroll
        for (int nt = 0; nt < 4; ++nt)
          acc[mt][nt] = __builtin_amdgcn_mfma_f32_16x16x32_bf16(ax, BWi[nt][j], acc[mt][nt], 0, 0, 0);
      }
      if (s + 1 < TT) {
        int tn = d ? (TT-2-s) : (s+1);
#pragma unroll
        for (int p = 0; p < 4; ++p) {
          int j = p >> 1, mt = p & 1;
          const float* px = x + (((size_t)(mt*16+lrow))*TT + tn)*512 + q*64 + j*32 + ksub;
          xr[p*2]   = *(const float4*)px;
          xr[p*2+1] = *(const float4*)(px + 4);
        }
      }
    } else {
      const u32 expx = ((u32)((s >> 4) & 1)) << 16;
      u32 mx = 0;
#pragma unroll
      for (int p = 0; p < 4; ++p)
#pragma unroll
        for (int hh = 0; hh < 2; ++hh)
#pragma unroll
          for (int e = 0; e < 4; ++e)
            mx |= ((u32)xm[p][hh][e]) ^ expx;
      if (!__all((int)(((mx >> 16) & 1u) == 0u)) && !dead) {
        const unsigned char* xs = plIn + (size_t)slot_w*PL_SLOT;
        int pit = 0;
        while (true) {
#pragma unroll
          for (int p = 0; p < 4; ++p) {
            int j = p >> 1, mt = p & 1;
            LD16(xm[p][0], xs + ao[j][mt]);
            LD16(xm[p][1], xs + ao[j][mt] + 16);
          }
          WAIT0();
          mx = 0;
#pragma unroll
          for (int p = 0; p < 4; ++p)
#pragma unroll
            for (int hh = 0; hh < 2; ++hh)
#pragma unroll
              for (int e = 0; e < 4; ++e)
                mx |= ((u32)xm[p][hh][e]) ^ expx;
          if (__all((int)(((mx >> 16) & 1u) == 0u))) break;
          ++pit;
          if (pit > 16) __builtin_amdgcn_s_sleep(1);
          if ((pit & 255) == 0) {
            if (sdead || __hip_atomic_load(abortf, __ATOMIC_RELAXED, __HIP_MEMORY_SCOPE_AGENT)) { dead = 1; break; }
            if (pit > (1 << 20)) {
              __hip_atomic_store(abortf, 1, __ATOMIC_RELAXED, __HIP_MEMORY_SCOPE_AGENT);
              sdead = 1; dead = 1; break;
            }
          }
        }
      }
#pragma unroll
      for (int p = 0; p < 4; ++p) {
        int j = p >> 1, mt = p & 1;
        i32x4 w0 = xm[p][0], w1 = xm[p][1];
        i32x4 hi4;
        hi4[0] = (int)(((u32)w0[0] & 0xFFFFu) | ((u32)w0[1] << 16));
        hi4[1] = (int)(((u32)w0[2] & 0xFFFFu) | ((u32)w0[3] << 16));
        hi4[2] = (int)(((u32)w1[0] & 0xFFFFu) | ((u32)w1[1] << 16));
        hi4[3] = (int)(((u32)w1[2] & 0xFFFFu) | ((u32)w1[3] << 16));
        bf16x8 ax = __builtin_bit_cast(bf16x8, hi4);
#pragma unroll
        for (int nt = 0; nt < 4; ++nt)
          acc[mt][nt] = __builtin_amdgcn_mfma_f32_16x16x32_bf16(ax, BWi[nt][j], acc[mt][nt], 0, 0, 0);
      }
      if (s + 1 < TT) {
        const unsigned char* xs2 = plIn + (size_t)((s + 1) & 15)*PL_SLOT;
#pragma unroll
        for (int p = 0; p < 4; ++p) {
          int j = p >> 1, mt = p & 1;
          LD16(xm[p][0], xs2 + ao[j][mt]);
          LD16(xm[p][1], xs2 + ao[j][mt] + 16);
        }
      }
    }

    // ---- h phase: split precision 3-term MFMA ----
#pragma unroll
    for (int p = 0; p < 4; ++p) {
      int j = p >> 1, mt = p & 1;
      i32x4 w0 = hw[p][0], w1 = hw[p][1];
      i32x4 hi4, lo4;
      hi4[0] = (int)(((u32)w0[0] & 0xFFFFu) | ((u32)w0[1] << 16));
      hi4[1] = (int)(((u32)w0[2] & 0xFFFFu) | ((u32)w0[3] << 16));
      hi4[2] = (int)(((u32)w1[0] & 0xFFFFu) | ((u32)w1[1] << 16));
      hi4[3] = (int)(((u32)w1[2] & 0xFFFFu) | ((u32)w1[3] << 16));
      lo4[0] = (int)(((u32)w0[0] >> 16) | ((u32)w0[1] & 0xFFFF0000u));
      lo4[1] = (int)(((u32)w0[2] >> 16) | ((u32)w0[3] & 0xFFFF0000u));
      lo4[2] = (int)(((u32)w1[0] >> 16) | ((u32)w1[1] & 0xFFFF0000u));
      lo4[3] = (int)(((u32)w1[2] >> 16) | ((u32)w1[3] & 0xFFFF0000u));
      bf16x8 ahi = __builtin_bit_cast(bf16x8, hi4);
      bf16x8 alo = __builtin_bit_cast(bf16x8, lo4);
#pragma unroll
      for (int nt = 0; nt < 4; ++nt) {
        acc[mt][nt] = __builtin_amdgcn_mfma_f32_16x16x32_bf16(ahi, BWh[nt][j],  acc[mt][nt], 0, 0, 0);
        acc[mt][nt] = __builtin_amdgcn_mfma_f32_16x16x32_bf16(alo, BWh[nt][j],  acc[mt][nt], 0, 0, 0);
        acc[mt][nt] = __builtin_amdgcn_mfma_f32_16x16x32_bf16(ahi, BWlo[nt][j], acc[mt][nt], 0, 0, 0);
      }
    }

    // ---- layer-0 ring throttle (protects layer-1's unread x slots) ----
    if (l == 0 && q == 0 && s >= 16) {
      int pit = 0;
      while (prog_cache < s - 15 && !dead) {
        prog_cache = __hip_atomic_load(prog1 + d, __ATOMIC_RELAXED, __HIP_MEMORY_SCOPE_AGENT);
        if (prog_cache < s - 15) {
          __builtin_amdgcn_s_sleep(2);
          if ((++pit & 255) == 0) {
            if (sdead || __hip_atomic_load(abortf, __ATOMIC_RELAXED, __HIP_MEMORY_SCOPE_AGENT)) dead = 1;
            if (pit > (1 << 20)) { __hip_atomic_store(abortf, 1, __ATOMIC_RELAXED, __HIP_MEMORY_SCOPE_AGENT); sdead = 1; dead = 1; }
          }
        }
      }
    }

    // ---- cross-wave K reduction (two-stage) ----
    __syncthreads();
    if (q >= 4) {
#pragma unroll
      for (int mt = 0; mt < 2; ++mt)
#pragma unroll
        for (int nt = 0; nt < 4; ++nt)
#pragma unroll
          for (int r = 0; r < 4; ++r)
            gb[q-4][mt*16 + (lane>>4)*4 + r][nt*16 + lrow] = acc[mt][nt][r];
    }
    __syncthreads();
    if (q < 4) {
#pragma unroll
      for (int mt = 0; mt < 2; ++mt)
#pragma unroll
        for (int nt = 0; nt < 4; ++nt)
#pragma unroll
          for (int r = 0; r < 4; ++r) {
            float* c = &gb[q][mt*16 + (lane>>4)*4 + r][nt*16 + lrow];
            *c = *c + acc[mt][nt][r];
          }
    }
    __syncthreads();

    float gi = bgi, gf = bgf, gg2 = bgg, go = bgo;
#pragma unroll
    for (int qq = 0; qq < 4; ++qq) {
      f32x4 pv = *(const f32x4*)&gb[qq][bthr][uthr*4];
      gi += pv[0]; gf += pv[1]; gg2 += pv[2]; go += pv[3];
    }
    float si = 1.f/(1.f + __expf(-gi));
    float sf = 1.f/(1.f + __expf(-gf));
    float so = 1.f/(1.f + __expf(-go));
    cst = sf*cst + si*tanhf(gg2);
    float h = so*tanhf(cst);

    bf16 hhv = (bf16)h;
    bf16 hlv = (bf16)(h - (float)hhv);
    u16 lob = (u16)((__builtin_bit_cast(u16, hlv) & 0xFFFEu) | (u16)par_w);
    u32 word = (u32)__builtin_bit_cast(u16, hhv) | ((u32)lob << 16);
    unsigned char* wp = plMain + (size_t)slot_w*PL_SLOT + (size_t)(bthr*512 + hu)*4;
    ST4(wp, word);
    if (l == 1) {
      H1p[((size_t)(s+1)*BB + bthr)*HH + hu] = hhv;          // plain store, read post-kernel
      if (w == 0 && tid == 0)
        __hip_atomic_store(prog1 + d, s, __ATOMIC_RELAXED, __HIP_MEMORY_SCOPE_AGENT);
    }
  }
}

#define SWZG(row, bc) ((u32)(row)*128u + ((u32)(bc) ^ ((((u32)(row))&7u)<<4)))

__launch_bounds__(256, 2)
__global__ void k_out(const unsigned char* __restrict__ ws,
                      const float* __restrict__ bout,
                      float* __restrict__ out) {
  __shared__ unsigned char As[64*128];
  __shared__ unsigned char Bs[128*128];
  const bf16* Hf = (const bf16*)(ws + OFF_H1);
  const bf16* Hb = Hf + H1_ELEM;
  const bf16* wbt = (const bf16*)(ws + OFF_WBT);

  const int m0 = blockIdx.x * 64;
  const int j0 = blockIdx.y * 128;
  const int tid = threadIdx.x, lane = tid & 63, q = tid >> 6;
  const int b = m0 >> 10;
  const int t0 = m0 & 1023;

  f32x4 acc[2][4];
#pragma unroll
  for (int mi = 0; mi < 2; ++mi)
#pragma unroll
    for (int ni = 0; ni < 4; ++ni) acc[mi][ni] = (f32x4){0.f,0.f,0.f,0.f};

  for (int kb = 0; kb < 16; ++kb) {
#pragma unroll
    for (int it = 0; it < 2; ++it) {
      int row = tid >> 2;
      int chunk = (tid & 3) + it*4;
      int k0 = kb*64 + chunk*8;
      int t = t0 + row;
      const bf16* src = (k0 < 512)
        ? (Hf + ((size_t)(t+1)*BB + b)*HH + k0)
        : (Hb + ((size_t)(TT - t)*BB + b)*HH + (k0 - 512));
      bf16x8 v = *(const bf16x8*)src;
#pragma unroll
      for (int e = 0; e < 8; ++e) { if ((float)v[e] < 0.f) v[e] = (bf16)0.f; }
      *(bf16x8*)(As + SWZG(row, chunk*16)) = v;
    }
#pragma unroll
    for (int it = 0; it < 4; ++it) {
      int j = (tid >> 3) + it*32;
      int chunk = tid & 7;
      int k0 = kb*64 + chunk*8;
      bf16x8 v = *(const bf16x8*)(wbt + (size_t)(j0+j)*1024 + k0);
      *(bf16x8*)(Bs + SWZG(j, chunk*16)) = v;
    }
    __syncthreads();
    const int mrow = (q & 1)*32;
    const int nc0 = (q >> 1)*64;
#pragma unroll
    for (int ks = 0; ks < 2; ++ks) {
      u32 koff = (u32)(ks*32 + (lane>>4)*8) * 2u;
      bf16x8 afr[2];
#pragma unroll
      for (int mi = 0; mi < 2; ++mi)
        afr[mi] = *(const bf16x8*)(As + SWZG(mrow + mi*16 + (lane&15), koff));
#pragma unroll
      for (int ni = 0; ni < 4; ++ni) {
        bf16x8 bfr = *(const bf16x8*)(Bs + SWZG(nc0 + ni*16 + (lane&15), koff));
#pragma unroll
        for (int mi = 0; mi < 2; ++mi)
          acc[mi][ni] = __builtin_amdgcn_mfma_f32_16x16x32_bf16(afr[mi], bfr, acc[mi][ni], 0, 0, 0);
      }
    }
    __syncthreads();
  }
#pragma unroll
  for (int ni = 0; ni < 4; ++ni) {
    int col = j0 + (q >> 1)*64 + ni*16 + (lane & 15);
    float bv = bout[col];
#pragma unroll
    for (int mi = 0; mi < 2; ++mi) {
#pragma unroll
      for (int r = 0; r < 4; ++r) {
        int m = m0 + (q & 1)*32 + mi*16 + (lane >> 4)*4 + r;
        out[(size_t)m*1024 + col] = acc[mi][ni][r] + bv;
      }
    }
  }
}

extern "C" void kernel_launch(void* const* d_in, const int* in_sizes, int n_in,
                              void* d_out, int out_size, void* d_ws, size_t ws_size,
                              hipStream_t stream) {
  const float* x    = (const float*)d_in[0];
  const float* h0   = (const float*)d_in[1];
  const float* c0   = (const float*)d_in[2];
  const float* Wi_f = (const float*)d_in[3];
  const float* Wh_f = (const float*)d_in[4];
  const float* b_f  = (const float*)d_in[5];
  const float* Wi_b = (const float*)d_in[6];
  const float* Wh_b = (const float*)d_in[7];
  const float* b_b  = (const float*)d_in[8];
  const float* Wo   = (const float*)d_in[9];
  const float* bo   = (const float*)d_in[10];
  unsigned char* ws = (unsigned char*)d_ws;
  float* out = (float*)d_out;

  hipLaunchKernelGGL(k_setup, dim3(2048), dim3(256), 0, stream,
                     h0, Wo, Wi_f, Wh_f, Wi_b, Wh_b, ws);

  void* args[] = { (void*)&x, (void*)&c0, (void*)&b_f, (void*)&b_b, (void*)&ws };
  hipError_t e = hipLaunchCooperativeKernel((const void*)k_rnn, dim3(256), dim3(512),
                                            args, 0, stream);
  if (e != hipSuccess) {
    // 256 blocks x 1/CU are co-resident under a normal launch too
    hipLaunchKernelGGL(k_rnn, dim3(256), dim3(512), 0, stream, x, c0, b_f, b_b, ws);
  }

  hipLaunchKernelGGL(k_out, dim3(512, 8), dim3(256), 0, stream,
                     (const unsigned char*)ws, bo, out);
}

// Round 8
// 10352.614 us; speedup vs baseline: 1.7198x; 1.7198x over previous
//
#include <hip/hip_runtime.h>
#include <math.h>

typedef __bf16 bf16;
typedef __bf16 bf16x8 __attribute__((ext_vector_type(8)));
typedef float f32x4 __attribute__((ext_vector_type(4)));
typedef int i32x4 __attribute__((ext_vector_type(4)));
typedef unsigned int u32;
typedef unsigned short u16;

#define TT 1024
#define BB 32
#define HH 512

// ---- workspace layout (bytes) ----
#define OFF_FLAGS 0ull                      // [4*1024 rows][64 words] = 1 MB
#define OFF_CTL   1048576ull                // abort int
#define OFF_WBT   (OFF_CTL + 1024ull)       // W_out^T bf16 [1024][1024] = 2 MB
#define OFF_FRAG  (OFF_WBT + 2097152ull)    // 3 x 8MB: Wi, Wh-hi, Wh-lo fragments
#define FRAG_B    8388608ull
#define OFF_PL    (OFF_FRAG + 3ull*FRAG_B)  // packed u32 planes: 4 grp x 16 slot x 64KB
#define PL_SLOT   65536ull
#define PL_GRP    (16ull*PL_SLOT)
#define OFF_H1    (OFF_PL + 4ull*PL_GRP)    // layer-1 h bf16: [2][1025*32*512]
#define H1_ELEM   ((size_t)(TT+1)*BB*HH)
// total ~= 95 MB

// plane word: low16 = bf16 hi(h), high16 = bf16 lo(h)
__global__ void k_setup(const float* __restrict__ h0, const float* __restrict__ wout,
                        const float* __restrict__ Wi_f, const float* __restrict__ Wh_f,
                        const float* __restrict__ Wi_b, const float* __restrict__ Wh_b,
                        unsigned char* __restrict__ ws) {
  const u32 N0 = 1048576;        // W_out^T
  const u32 N1 = 65536;          // plane slot 15 = h0
  const u32 N3 = 2097152;        // Wi fragments (1 word = 2 elems)
  const u32 N4 = 2097152;        // Wh fragments (hi + lo)
  const u32 N5 = 262145;         // flags + abort
  const u32 total = N0 + N1 + N3 + N4 + N5;
  for (u32 i = blockIdx.x*blockDim.x + threadIdx.x; i < total; i += gridDim.x*blockDim.x) {
    if (i < N0) {
      u32 jj = i >> 10, kk = i & 1023u;
      ((bf16*)(ws + OFF_WBT))[(size_t)jj*1024 + kk] = (bf16)wout[(size_t)kk*1024 + jj];
    } else if (i < N0 + N1) {
      u32 t = i - N0;
      u32 g = t >> 14, r = t & 16383u;
      u32 b = r >> 9, u = r & 511u, l = g >> 1;
      float v = h0[((size_t)l*BB + b)*HH + u];
      bf16 hi = (bf16)v;
      bf16 lo = (bf16)(v - (float)hi);
      u32 word = (u32)__builtin_bit_cast(u16, hi) | ((u32)__builtin_bit_cast(u16, lo) << 16);
      *(u32*)(ws + OFF_PL + (size_t)g*PL_GRP + 15ull*PL_SLOT + (size_t)r*4) = word;
    } else if (i < N0 + N1 + N3 + N4) {
      u32 t = i - N0 - N1;
      int isWh = (t >= N3);
      if (isWh) t -= N3;
      u32 e2 = t & 3u, lane = (t>>2)&63u, nt = (t>>8)&1u, j = (t>>9)&3u;
      u32 q = (t>>11)&3u, w2 = (t>>13)&63u, g = (t>>19)&3u;
      u32 l = g >> 1, d = g & 1;
      u32 lrow = lane & 15u, kr0 = (lane>>4)*8u;
      u32 cc = nt*16 + lrow;
      u32 unit = cc >> 2, gate = cc & 3u;
      u32 J = gate*512 + w2*8 + unit;
      u32 k = (q*4 + j)*32 + kr0 + e2*2;
      const float* src = isWh ? ((d ? Wh_b : Wh_f) + (size_t)l*HH*2048)
                              : ((d ? Wi_b : Wi_f) + (size_t)l*HH*2048);
      float v0 = src[(size_t)k*2048 + J];
      float v1 = src[(size_t)(k+1)*2048 + J];
      size_t fo = ((((size_t)(g*64+w2)*4 + q)*4 + j)*2 + nt)*64 + lane;
      size_t byte = fo*16 + e2*4;
      if (!isWh) {
        *(u32*)(ws + OFF_FRAG + byte) =
          (u32)__builtin_bit_cast(u16,(bf16)v0) | ((u32)__builtin_bit_cast(u16,(bf16)v1) << 16);
      } else {
        bf16 h0b = (bf16)v0, h1b = (bf16)v1;
        bf16 l0b = (bf16)(v0 - (float)h0b), l1b = (bf16)(v1 - (float)h1b);
        *(u32*)(ws + OFF_FRAG + FRAG_B + byte) =
          (u32)__builtin_bit_cast(u16,h0b) | ((u32)__builtin_bit_cast(u16,h1b) << 16);
        *(u32*)(ws + OFF_FRAG + 2ull*FRAG_B + byte) =
          (u32)__builtin_bit_cast(u16,l0b) | ((u32)__builtin_bit_cast(u16,l1b) << 16);
      }
    } else {
      u32 t = i - (N0+N1+N3+N4);
      if (t < 262144u) ((int*)(ws + OFF_FLAGS))[t] = 0;
      else *(int*)(ws + OFF_CTL) = 0;
    }
  }
}

#define LD16(dst, p) asm volatile("global_load_dwordx4 %0, %1, off sc0 sc1" : "=v"(dst) : "v"(p) : "memory")
#define ST4(p, v)    asm volatile("global_store_dword %0, %1, off sc0 sc1" :: "v"(p), "v"(v) : "memory")
#define WAIT0() do { asm volatile("s_waitcnt vmcnt(0)" ::: "memory"); __builtin_amdgcn_sched_barrier(0); } while (0)

// round-2-proven flag poll: relaxed spin + final acquire
__device__ __forceinline__ bool pollrow64(int* row, int lane, int* abortf) {
  int it = 0;
  while (true) {
    int v = __hip_atomic_load(row + lane, __ATOMIC_RELAXED, __HIP_MEMORY_SCOPE_AGENT);
    if (__all(v != 0)) {
      (void)__hip_atomic_load(row + lane, __ATOMIC_ACQUIRE, __HIP_MEMORY_SCOPE_AGENT);
      return true;
    }
    ++it;
    if (it > 32) __builtin_amdgcn_s_sleep(1);
    if ((it & 255) == 0) {
      if (__hip_atomic_load(abortf, __ATOMIC_RELAXED, __HIP_MEMORY_SCOPE_AGENT)) return false;
      if (it > (1 << 20)) {
        __hip_atomic_store(abortf, 1, __ATOMIC_RELAXED, __HIP_MEMORY_SCOPE_AGENT);
        return false;
      }
    }
  }
}

__launch_bounds__(256, 1)
__global__ void k_rnn(const float* __restrict__ x, const float* __restrict__ c0,
                      const float* __restrict__ b_f, const float* __restrict__ b_b,
                      unsigned char* __restrict__ ws) {
  __shared__ float gb[4][32][33];
  __shared__ int sdead;

  const int bid = blockIdx.x;
  const int g = bid & 3;            // layer*2 + dir (round-robins groups over XCDs)
  const int w = bid >> 2;           // 0..63, owns units w*8..w*8+7
  const int l = g >> 1, d = g & 1;
  const int tid = threadIdx.x;
  const int lane = tid & 63;
  const int q = tid >> 6;           // wave 0..3, owns ks = q*4..q*4+3
  const int lrow = lane & 15;
  const int kr0 = (lane >> 4) * 8;

  int* abortf = (int*)(ws + OFF_CTL);
  int* flagw  = (int*)(ws + OFF_FLAGS);

  if (tid == 0) sdead = 0;

  // ---- pre-packed weight fragments (coalesced 16B loads; proven round 4) ----
  bf16x8 BWi[4][2], BWh[4][2], BWlo[4][2];
#pragma unroll
  for (int j = 0; j < 4; ++j)
#pragma unroll
    for (int nt = 0; nt < 2; ++nt) {
      size_t fo = (((((size_t)(g*64+w)*4 + q)*4 + j)*2 + nt)*64 + lane) * 16;
      BWi[j][nt]  = *(const bf16x8*)(ws + OFF_FRAG + fo);
      BWh[j][nt]  = *(const bf16x8*)(ws + OFF_FRAG + FRAG_B + fo);
      BWlo[j][nt] = *(const bf16x8*)(ws + OFF_FRAG + 2ull*FRAG_B + fo);
    }

  const int bthr = tid >> 3, uthr = tid & 7;
  const int hu = w*8 + uthr;
  float cst = c0[((size_t)l*BB + bthr)*HH + hu];
  const float* bias = (d ? b_b : b_f) + (size_t)l*2048;
  const float bgi = bias[hu], bgf = bias[512+hu], bgg = bias[1024+hu], bgo = bias[1536+hu];

  unsigned char* plOwn = ws + OFF_PL + (size_t)g*PL_GRP;
  const unsigned char* plIn = ws + OFF_PL + (size_t)d*PL_GRP;   // layer-0 plane (x for layer 1)
  bf16* H1p = (bf16*)(ws + OFF_H1) + (size_t)d*H1_ELEM;

  u32 ao[4][2];
#pragma unroll
  for (int j = 0; j < 4; ++j)
#pragma unroll
    for (int mt = 0; mt < 2; ++mt)
      ao[j][mt] = (u32)((((mt*16 + lrow)*512) + (q*4 + j)*32 + kr0) * 4);

  __syncthreads();

  // ---- layer-0 x prefetch: FULL 8 fragments (j=0..3 x mt=0..1) ----
  // (rounds 5-7 bug: only 4 fragments were prefetched while 8 were consumed)
  float4 xr[16];
  if (l == 0) {
    int t0i = d ? (TT-1) : 0;
#pragma unroll
    for (int f = 0; f < 8; ++f) {
      int j = f >> 1, mt = f & 1;
      const float* px = x + (((size_t)(mt*16+lrow))*TT + t0i)*512 + (q*4 + j)*32 + kr0;
      xr[f*2]   = *(const float4*)px;
      xr[f*2+1] = *(const float4*)(px + 4);
    }
  }

  for (int s = 0; s < TT; ++s) {
    const int slot_w = s & 15;

    if (l == 1) {
      // gate this step's x-input (layer-0's h(s) in slot s&15)
      if (q == 1) { if (!pollrow64(flagw + (size_t)(d*1024 + s)*64, lane, abortf)) sdead = 1; }
      __syncthreads();                     // barrier A
    }

    f32x4 acc[2][2];
#pragma unroll
    for (int mt = 0; mt < 2; ++mt)
#pragma unroll
      for (int nt = 0; nt < 2; ++nt) acc[mt][nt] = (f32x4){0.f,0.f,0.f,0.f};

    // ---- x phase (polls overlap compute/load latency; proven round-2 order) ----
    if (l == 0) {
      if (q == 0 && s > 0)  { if (!pollrow64(flagw + (size_t)(g*1024 + s-1)*64, lane, abortf)) sdead = 1; }
      if (q == 1 && s >= 16){ if (!pollrow64(flagw + (size_t)((2+d)*1024 + s-16)*64, lane, abortf)) sdead = 1; }
#pragma unroll
      for (int f = 0; f < 8; ++f) {
        int j = f >> 1, mt = f & 1;
        float4 a = xr[f*2], b4 = xr[f*2+1];
        bf16x8 ax = { (bf16)a.x,(bf16)a.y,(bf16)a.z,(bf16)a.w,
                      (bf16)b4.x,(bf16)b4.y,(bf16)b4.z,(bf16)b4.w };
#pragma unroll
        for (int nt = 0; nt < 2; ++nt)
          acc[mt][nt] = __builtin_amdgcn_mfma_f32_16x16x32_bf16(ax, BWi[j][nt], acc[mt][nt], 0, 0, 0);
      }
      if (s + 1 < TT) {                    // prefetch next x (plain cached loads)
        int tn = d ? (TT-2-s) : (s+1);
#pragma unroll
        for (int f = 0; f < 8; ++f) {
          int j = f >> 1, mt = f & 1;
          const float* px = x + (((size_t)(mt*16+lrow))*TT + tn)*512 + (q*4 + j)*32 + kr0;
          xr[f*2]   = *(const float4*)px;
          xr[f*2+1] = *(const float4*)(px + 4);
        }
      }
    } else {
      const unsigned char* xs = plIn + (size_t)slot_w*PL_SLOT;
      i32x4 xm[4][2][2];
#pragma unroll
      for (int j = 0; j < 4; ++j)
#pragma unroll
        for (int mt = 0; mt < 2; ++mt) {
          LD16(xm[j][mt][0], xs + ao[j][mt]);
          LD16(xm[j][mt][1], xs + ao[j][mt] + 16);
        }
      if (q == 0 && s > 0) { if (!pollrow64(flagw + (size_t)(g*1024 + s-1)*64, lane, abortf)) sdead = 1; }
      WAIT0();
#pragma unroll
      for (int j = 0; j < 4; ++j)
#pragma unroll
        for (int mt = 0; mt < 2; ++mt) {
          i32x4 w0 = xm[j][mt][0], w1 = xm[j][mt][1];
          i32x4 hi4;
          hi4[0] = (int)(((u32)w0[0] & 0xFFFFu) | ((u32)w0[1] << 16));
          hi4[1] = (int)(((u32)w0[2] & 0xFFFFu) | ((u32)w0[3] << 16));
          hi4[2] = (int)(((u32)w1[0] & 0xFFFFu) | ((u32)w1[1] << 16));
          hi4[3] = (int)(((u32)w1[2] & 0xFFFFu) | ((u32)w1[3] << 16));
          bf16x8 ax = __builtin_bit_cast(bf16x8, hi4);
#pragma unroll
          for (int nt = 0; nt < 2; ++nt)
            acc[mt][nt] = __builtin_amdgcn_mfma_f32_16x16x32_bf16(ax, BWi[j][nt], acc[mt][nt], 0, 0, 0);
        }
    }
    __syncthreads();                       // barrier B
    if (sdead) return;

    // ---- h phase: packed-word loads, split-precision 3-term MFMAs ----
    const unsigned char* hs = plOwn + (size_t)((s + 15) & 15)*PL_SLOT;
    i32x4 hw[4][2][2];
#pragma unroll
    for (int j = 0; j < 4; ++j)
#pragma unroll
      for (int mt = 0; mt < 2; ++mt) {
        LD16(hw[j][mt][0], hs + ao[j][mt]);
        LD16(hw[j][mt][1], hs + ao[j][mt] + 16);
      }
    WAIT0();
#pragma unroll
    for (int j = 0; j < 4; ++j)
#pragma unroll
      for (int mt = 0; mt < 2; ++mt) {
        i32x4 w0 = hw[j][mt][0], w1 = hw[j][mt][1];
        i32x4 hi4, lo4;
        hi4[0] = (int)(((u32)w0[0] & 0xFFFFu) | ((u32)w0[1] << 16));
        hi4[1] = (int)(((u32)w0[2] & 0xFFFFu) | ((u32)w0[3] << 16));
        hi4[2] = (int)(((u32)w1[0] & 0xFFFFu) | ((u32)w1[1] << 16));
        hi4[3] = (int)(((u32)w1[2] & 0xFFFFu) | ((u32)w1[3] << 16));
        lo4[0] = (int)(((u32)w0[0] >> 16) | ((u32)w0[1] & 0xFFFF0000u));
        lo4[1] = (int)(((u32)w0[2] >> 16) | ((u32)w0[3] & 0xFFFF0000u));
        lo4[2] = (int)(((u32)w1[0] >> 16) | ((u32)w1[1] & 0xFFFF0000u));
        lo4[3] = (int)(((u32)w1[2] >> 16) | ((u32)w1[3] & 0xFFFF0000u));
        bf16x8 ahi = __builtin_bit_cast(bf16x8, hi4);
        bf16x8 alo = __builtin_bit_cast(bf16x8, lo4);
#pragma unroll
        for (int nt = 0; nt < 2; ++nt) {
          acc[mt][nt] = __builtin_amdgcn_mfma_f32_16x16x32_bf16(ahi, BWh[j][nt],  acc[mt][nt], 0, 0, 0);
          acc[mt][nt] = __builtin_amdgcn_mfma_f32_16x16x32_bf16(alo, BWh[j][nt],  acc[mt][nt], 0, 0, 0);
          acc[mt][nt] = __builtin_amdgcn_mfma_f32_16x16x32_bf16(ahi, BWlo[j][nt], acc[mt][nt], 0, 0, 0);
        }
      }

    // ---- cross-wave K reduction via LDS ----
#pragma unroll
    for (int mt = 0; mt < 2; ++mt)
#pragma unroll
      for (int nt = 0; nt < 2; ++nt)
#pragma unroll
        for (int r = 0; r < 4; ++r)
          gb[q][mt*16 + (lane>>4)*4 + r][nt*16 + lrow] = acc[mt][nt][r];
    __syncthreads();                       // barrier C

    float gi = bgi, gf = bgf, gg2 = bgg, go = bgo;
#pragma unroll
    for (int qq = 0; qq < 4; ++qq) {
      gi  += gb[qq][bthr][uthr*4 + 0];
      gf  += gb[qq][bthr][uthr*4 + 1];
      gg2 += gb[qq][bthr][uthr*4 + 2];
      go  += gb[qq][bthr][uthr*4 + 3];
    }
    float si = 1.f/(1.f + __expf(-gi));
    float sf = 1.f/(1.f + __expf(-gf));
    float so = 1.f/(1.f + __expf(-go));
    cst = sf*cst + si*tanhf(gg2);
    float h = so*tanhf(cst);

    bf16 hhv = (bf16)h;
    bf16 hlv = (bf16)(h - (float)hhv);
    u32 word = (u32)__builtin_bit_cast(u16, hhv) | ((u32)__builtin_bit_cast(u16, hlv) << 16);
    ST4(plOwn + (size_t)slot_w*PL_SLOT + (size_t)(bthr*512 + hu)*4, word);
    if (l == 1)
      H1p[((size_t)(s+1)*BB + bthr)*HH + hu] = hhv;          // plain store, read post-kernel

    WAIT0();                               // drain exchange stores
    __syncthreads();                       // barrier D: all waves' stores drained
    if (tid == 0)
      __hip_atomic_store(flagw + (size_t)(g*1024 + s)*64 + w, 1,
                         __ATOMIC_RELAXED, __HIP_MEMORY_SCOPE_AGENT);
  }
}

#define SWZG(row, bc) ((u32)(row)*128u + ((u32)(bc) ^ ((((u32)(row))&7u)<<4)))

__launch_bounds__(256, 2)
__global__ void k_out(const unsigned char* __restrict__ ws,
                      const float* __restrict__ bout,
                      float* __restrict__ out) {
  __shared__ unsigned char As[64*128];
  __shared__ unsigned char Bs[128*128];
  const bf16* Hf = (const bf16*)(ws + OFF_H1);
  const bf16* Hb = Hf + H1_ELEM;
  const bf16* wbt = (const bf16*)(ws + OFF_WBT);

  const int m0 = blockIdx.x * 64;
  const int j0 = blockIdx.y * 128;
  const int tid = threadIdx.x, lane = tid & 63, q = tid >> 6;
  const int b = m0 >> 10;
  const int t0 = m0 & 1023;

  f32x4 acc[2][4];
#pragma unroll
  for (int mi = 0; mi < 2; ++mi)
#pragma unroll
    for (int ni = 0; ni < 4; ++ni) acc[mi][ni] = (f32x4){0.f,0.f,0.f,0.f};

  for (int kb = 0; kb < 16; ++kb) {
#pragma unroll
    for (int it = 0; it < 2; ++it) {
      int row = tid >> 2;
      int chunk = (tid & 3) + it*4;
      int k0 = kb*64 + chunk*8;
      int t = t0 + row;
      const bf16* src = (k0 < 512)
        ? (Hf + ((size_t)(t+1)*BB + b)*HH + k0)
        : (Hb + ((size_t)(TT - t)*BB + b)*HH + (k0 - 512));
      bf16x8 v = *(const bf16x8*)src;
#pragma unroll
      for (int e = 0; e < 8; ++e) { if ((float)v[e] < 0.f) v[e] = (bf16)0.f; }
      *(bf16x8*)(As + SWZG(row, chunk*16)) = v;
    }
#pragma unroll
    for (int it = 0; it < 4; ++it) {
      int j = (tid >> 3) + it*32;
      int chunk = tid & 7;
      int k0 = kb*64 + chunk*8;
      bf16x8 v = *(const bf16x8*)(wbt + (size_t)(j0+j)*1024 + k0);
      *(bf16x8*)(Bs + SWZG(j, chunk*16)) = v;
    }
    __syncthreads();
    const int mrow = (q & 1)*32;
    const int nc0 = (q >> 1)*64;
#pragma unroll
    for (int ks = 0; ks < 2; ++ks) {
      u32 koff = (u32)(ks*32 + (lane>>4)*8) * 2u;
      bf16x8 afr[2];
#pragma unroll
      for (int mi = 0; mi < 2; ++mi)
        afr[mi] = *(const bf16x8*)(As + SWZG(mrow + mi*16 + (lane&15), koff));
#pragma unroll
      for (int ni = 0; ni < 4; ++ni) {
        bf16x8 bfr = *(const bf16x8*)(Bs + SWZG(nc0 + ni*16 + (lane&15), koff));
#pragma unroll
        for (int mi = 0; mi < 2; ++mi)
          acc[mi][ni] = __builtin_amdgcn_mfma_f32_16x16x32_bf16(afr[mi], bfr, acc[mi][ni], 0, 0, 0);
      }
    }
    __syncthreads();
  }
#pragma unroll
  for (int ni = 0; ni < 4; ++ni) {
    int col = j0 + (q >> 1)*64 + ni*16 + (lane & 15);
    float bv = bout[col];
#pragma unroll
    for (int mi = 0; mi < 2; ++mi) {
#pragma unroll
      for (int r = 0; r < 4; ++r) {
        int m = m0 + (q & 1)*32 + mi*16 + (lane >> 4)*4 + r;
        out[(size_t)m*1024 + col] = acc[mi][ni][r] + bv;
      }
    }
  }
}

extern "C" void kernel_launch(void* const* d_in, const int* in_sizes, int n_in,
                              void* d_out, int out_size, void* d_ws, size_t ws_size,
                              hipStream_t stream) {
  const float* x    = (const float*)d_in[0];
  const float* h0   = (const float*)d_in[1];
  const float* c0   = (const float*)d_in[2];
  const float* Wi_f = (const float*)d_in[3];
  const float* Wh_f = (const float*)d_in[4];
  const float* b_f  = (const float*)d_in[5];
  const float* Wi_b = (const float*)d_in[6];
  const float* Wh_b = (const float*)d_in[7];
  const float* b_b  = (const float*)d_in[8];
  const float* Wo   = (const float*)d_in[9];
  const float* bo   = (const float*)d_in[10];
  unsigned char* ws = (unsigned char*)d_ws;
  float* out = (float*)d_out;

  hipLaunchKernelGGL(k_setup, dim3(2048), dim3(256), 0, stream,
                     h0, Wo, Wi_f, Wh_f, Wi_b, Wh_b, ws);

  void* args[] = { (void*)&x, (void*)&c0, (void*)&b_f, (void*)&b_b, (void*)&ws };
  hipError_t e = hipLaunchCooperativeKernel((const void*)k_rnn, dim3(256), dim3(256),
                                            args, 0, stream);
  if (e != hipSuccess) {
    // 256 blocks x 256 threads (1/CU) are co-resident under a normal launch too
    hipLaunchKernelGGL(k_rnn, dim3(256), dim3(256), 0, stream, x, c0, b_f, b_b, ws);
  }

  hipLaunchKernelGGL(k_out, dim3(512, 8), dim3(256), 0, stream,
                     (const unsigned char*)ws, bo, out);
}

// Round 10
// 6761.122 us; speedup vs baseline: 2.6333x; 1.5312x over previous
//
#include <hip/hip_runtime.h>
#include <math.h>

typedef __bf16 bf16;
typedef __bf16 bf16x8 __attribute__((ext_vector_type(8)));
typedef float f32x4 __attribute__((ext_vector_type(4)));
typedef int i32x4 __attribute__((ext_vector_type(4)));
typedef unsigned int u32;
typedef unsigned short u16;

#define TT 1024
#define BB 32
#define HH 512

// ---- workspace layout (bytes) ----
#define OFF_FLAGS 0ull                      // [4*1024 rows][64 ints] = 1 MB
#define OFF_CTL   1048576ull                // abort int
#define OFF_WBT   (OFF_CTL + 1024ull)       // W_out^T bf16 [1024][1024] = 2 MB
#define OFF_FRAG  (OFF_WBT + 2097152ull)    // 3 x 8MB: Wi, Wh-hi, Wh-lo fragments
#define FRAG_B    8388608ull
#define OFF_PL    (OFF_FRAG + 3ull*FRAG_B)  // packed u32 planes: 4 grp x 16 slot x 64KB
#define PL_SLOT   65536ull
#define PL_GRP    (16ull*PL_SLOT)
#define PLP(gg, slot) (ws + OFF_PL + ((size_t)(gg)*PL_GRP + (size_t)(slot)*PL_SLOT))
#define OFF_H1    (OFF_PL + 4ull*PL_GRP)    // layer-1 h bf16: [2][1025*32*512]
#define H1_ELEM   ((size_t)(TT+1)*BB*HH)
// total ~= 1 + 2 + 24 + 4 + 67 ~= 98 MB

// plane word (round-4-proven, word-atomic): low16 = bf16 hi(h),
// high16 = bf16 lo(h) with LSB (bit 16) = lap parity ((s>>4)&1).
__global__ void k_setup(const float* __restrict__ h0, const float* __restrict__ wout,
                        const float* __restrict__ Wi_f, const float* __restrict__ Wh_f,
                        const float* __restrict__ Wi_b, const float* __restrict__ Wh_b,
                        unsigned char* __restrict__ ws) {
  const u32 N0 = 1048576;        // W_out^T
  const u32 N1 = 1048576;        // plane init: all 4 grp x 16 slots x 16384 words
  const u32 N3 = 2097152;        // Wi fragments (1 item = 2 elems)
  const u32 N4 = 2097152;        // Wh fragments (hi + lo)
  const u32 N5 = 262145;         // flags + abort
  const u32 total = N0 + N1 + N3 + N4 + N5;
  for (u32 i = blockIdx.x*blockDim.x + threadIdx.x; i < total; i += gridDim.x*blockDim.x) {
    if (i < N0) {
      u32 jj = i >> 10, kk = i & 1023u;
      ((bf16*)(ws + OFF_WBT))[(size_t)jj*1024 + kk] = (bf16)wout[(size_t)kk*1024 + jj];
    } else if (i < N0 + N1) {
      u32 t = i - N0;
      u32 g = t >> 18, rem = t & 262143u;
      u32 slot = rem >> 14, r = rem & 16383u;
      u32 word = 0x00010000u;                    // parity-1 poison
      if (slot == 15) {                          // slot 15 = h(-1) = h0, parity 1
        u32 b = r >> 9, u = r & 511u, l = g >> 1;
        float v = h0[((size_t)l*BB + b)*HH + u];
        bf16 hi = (bf16)v;
        bf16 lo = (bf16)(v - (float)hi);
        u16 lob = (u16)((__builtin_bit_cast(u16, lo) & 0xFFFEu) | 1u);
        word = (u32)__builtin_bit_cast(u16, hi) | ((u32)lob << 16);
      }
      *(u32*)(PLP(g, slot) + (size_t)r*4) = word;
    } else if (i < N0 + N1 + N3 + N4) {
      u32 t = i - N0 - N1;
      int isWh = (t >= N3);
      if (isWh) t -= N3;
      u32 e2 = t & 3u, lane = (t>>2)&63u, nt = (t>>8)&1u, j = (t>>9)&3u;
      u32 q = (t>>11)&3u, w2 = (t>>13)&63u, g = (t>>19)&3u;
      u32 l = g >> 1, d = g & 1;
      u32 lrow = lane & 15u, kr0 = (lane>>4)*8u;
      u32 cc = nt*16 + lrow;
      u32 unit = cc >> 2, gate = cc & 3u;
      u32 J = gate*512 + w2*8 + unit;
      u32 k = (q*4 + j)*32 + kr0 + e2*2;
      const float* src = isWh ? ((d ? Wh_b : Wh_f) + (size_t)l*HH*2048)
                              : ((d ? Wi_b : Wi_f) + (size_t)l*HH*2048);
      float v0 = src[(size_t)k*2048 + J];
      float v1 = src[(size_t)(k+1)*2048 + J];
      size_t fo = ((((size_t)(g*64+w2)*4 + q)*4 + j)*2 + nt)*64 + lane;
      size_t byte = fo*16 + e2*4;
      if (!isWh) {
        *(u32*)(ws + OFF_FRAG + byte) =
          (u32)__builtin_bit_cast(u16,(bf16)v0) | ((u32)__builtin_bit_cast(u16,(bf16)v1) << 16);
      } else {
        bf16 h0b = (bf16)v0, h1b = (bf16)v1;
        bf16 l0b = (bf16)(v0 - (float)h0b), l1b = (bf16)(v1 - (float)h1b);
        *(u32*)(ws + OFF_FRAG + FRAG_B + byte) =
          (u32)__builtin_bit_cast(u16,h0b) | ((u32)__builtin_bit_cast(u16,h1b) << 16);
        *(u32*)(ws + OFF_FRAG + 2ull*FRAG_B + byte) =
          (u32)__builtin_bit_cast(u16,l0b) | ((u32)__builtin_bit_cast(u16,l1b) << 16);
      }
    } else {
      u32 t = i - (N0+N1+N3+N4);
      if (t < 262144u) ((int*)(ws + OFF_FLAGS))[t] = 0;
      else *(int*)(ws + OFF_CTL) = 0;
    }
  }
}

#define LD16(dst, p) asm volatile("global_load_dwordx4 %0, %1, off sc0 sc1" : "=v"(dst) : "v"(p) : "memory")
#define ST4(p, v)    asm volatile("global_store_dword %0, %1, off sc0 sc1" :: "v"(p), "v"(v) : "memory")
#define WAIT0() do { asm volatile("s_waitcnt vmcnt(0)" ::: "memory"); __builtin_amdgcn_sched_barrier(0); } while (0)

// round-2-proven flag poll: relaxed loads only (payload loads bypass caches;
// producer's vmcnt(0)-before-flag provides the ordering).
__device__ __forceinline__ bool pollrow64(int* row, int lane, int* abortf) {
  int it = 0;
  while (true) {
    int v = __hip_atomic_load(row + lane, __ATOMIC_RELAXED, __HIP_MEMORY_SCOPE_AGENT);
    if (__all(v != 0)) return true;
    ++it;
    if (it > 32) __builtin_amdgcn_s_sleep(1);
    if ((it & 255) == 0) {
      if (__hip_atomic_load(abortf, __ATOMIC_RELAXED, __HIP_MEMORY_SCOPE_AGENT)) return false;
      if (it > (1 << 20)) {
        __hip_atomic_store(abortf, 1, __ATOMIC_RELAXED, __HIP_MEMORY_SCOPE_AGENT);
        return false;
      }
    }
  }
}

__launch_bounds__(256, 1)
__global__ void k_rnn(const float* __restrict__ x, const float* __restrict__ c0,
                      const float* __restrict__ b_f, const float* __restrict__ b_b,
                      unsigned char* __restrict__ ws) {
  __shared__ float gb[4][32][33];
  __shared__ int sdead;

  const int bid = blockIdx.x;
  const int g = bid & 3;            // layer*2 + dir
  const int w = bid >> 2;           // 0..63, owns units w*8..w*8+7
  const int l = g >> 1, d = g & 1;
  const int tid = threadIdx.x;
  const int lane = tid & 63;
  const int q = tid >> 6;           // wave 0..3, owns ks = q*4..q*4+3
  const int lrow = lane & 15;
  const int kr0 = (lane >> 4) * 8;

  int* abortf = (int*)(ws + OFF_CTL);
  int* flagw  = (int*)(ws + OFF_FLAGS);

  if (tid == 0) sdead = 0;

  // ---- pre-packed weight fragments (coalesced 16B loads; proven R4/R8) ----
  bf16x8 BWi[4][2], BWh[4][2], BWlo[4][2];
#pragma unroll
  for (int j = 0; j < 4; ++j)
#pragma unroll
    for (int nt = 0; nt < 2; ++nt) {
      size_t fo = (((((size_t)(g*64+w)*4 + q)*4 + j)*2 + nt)*64 + lane) * 16;
      BWi[j][nt]  = *(const bf16x8*)(ws + OFF_FRAG + fo);
      BWh[j][nt]  = *(const bf16x8*)(ws + OFF_FRAG + FRAG_B + fo);
      BWlo[j][nt] = *(const bf16x8*)(ws + OFF_FRAG + 2ull*FRAG_B + fo);
    }

  const int bthr = tid >> 3, uthr = tid & 7;
  const int hu = w*8 + uthr;
  float cst = c0[((size_t)l*BB + bthr)*HH + hu];
  const float* bias = (d ? b_b : b_f) + (size_t)l*2048;
  const float bgi = bias[hu], bgf = bias[512+hu], bgg = bias[1024+hu], bgo = bias[1536+hu];

  bf16* H1p = (bf16*)(ws + OFF_H1) + (size_t)d*H1_ELEM;

  // byte offsets within a 64KB packed-u32 plane (4 B per element)
  u32 ao[4][2];
#pragma unroll
  for (int j = 0; j < 4; ++j)
#pragma unroll
    for (int mt = 0; mt < 2; ++mt)
      ao[j][mt] = (u32)((((mt*16 + lrow)*512) + (q*4 + j)*32 + kr0) * 4);

  __syncthreads();

  for (int s = 0; s < TT; ++s) {
    const int slot_w = s & 15;
    const u32 par_w = (u32)((s >> 4) & 1);

    f32x4 acc[2][2];
#pragma unroll
    for (int mt = 0; mt < 2; ++mt)
#pragma unroll
      for (int nt = 0; nt < 2; ++nt) acc[mt][nt] = (f32x4){0.f,0.f,0.f,0.f};

    // ---- x phase ----
    if (l == 0) {
      const int t_time = d ? (TT-1-s) : s;
      bf16x8 Ax[4][2];
#pragma unroll
      for (int j = 0; j < 4; ++j)
#pragma unroll
        for (int mt = 0; mt < 2; ++mt) {
          const float* px = x + (((size_t)(mt*16+lrow))*TT + t_time)*512 + (q*4 + j)*32 + kr0;
          float4 a  = *(const float4*)px;
          float4 b4 = *(const float4*)(px + 4);
          Ax[j][mt] = (bf16x8){ (bf16)a.x,(bf16)a.y,(bf16)a.z,(bf16)a.w,
                                (bf16)b4.x,(bf16)b4.y,(bf16)b4.z,(bf16)b4.w };
        }
      if (q == 0 && s > 0)   { if (!pollrow64(flagw + (size_t)(g*1024 + s-1)*64, lane, abortf)) sdead = 1; }
      if (q == 1 && s >= 16) { if (!pollrow64(flagw + (size_t)((2+d)*1024 + s-16)*64, lane, abortf)) sdead = 1; }
#pragma unroll
      for (int j = 0; j < 4; ++j)
#pragma unroll
        for (int mt = 0; mt < 2; ++mt)
#pragma unroll
          for (int nt = 0; nt < 2; ++nt)
            acc[mt][nt] = __builtin_amdgcn_mfma_f32_16x16x32_bf16(Ax[j][mt], BWi[j][nt], acc[mt][nt], 0, 0, 0);
    } else {
      // speculative x read of layer-0's plane; every consumed WORD self-validates
      // via the parity bit (word-atomic packed format -> no hi/lo tearing).
      const unsigned char* xs = PLP(d, slot_w);
      i32x4 xm[4][2][2];
#pragma unroll
      for (int j = 0; j < 4; ++j)
#pragma unroll
        for (int mt = 0; mt < 2; ++mt) {
          LD16(xm[j][mt][0], xs + ao[j][mt]);
          LD16(xm[j][mt][1], xs + ao[j][mt] + 16);
        }
      if (q == 0 && s > 0) { if (!pollrow64(flagw + (size_t)(g*1024 + s-1)*64, lane, abortf)) sdead = 1; }
      WAIT0();
      const u32 expP = par_w << 16;
      u32 m = 0;
#pragma unroll
      for (int j = 0; j < 4; ++j)
#pragma unroll
        for (int mt = 0; mt < 2; ++mt)
#pragma unroll
          for (int hh = 0; hh < 2; ++hh)
#pragma unroll
            for (int e = 0; e < 4; ++e)
              m |= (((u32)xm[j][mt][hh][e]) ^ expP) & 0x00010000u;
      if (!__all((int)(m == 0u))) {
        int pit = 0;
        while (true) {
#pragma unroll
          for (int j = 0; j < 4; ++j)
#pragma unroll
            for (int mt = 0; mt < 2; ++mt) {
              LD16(xm[j][mt][0], xs + ao[j][mt]);
              LD16(xm[j][mt][1], xs + ao[j][mt] + 16);
            }
          WAIT0();
          m = 0;
#pragma unroll
          for (int j = 0; j < 4; ++j)
#pragma unroll
            for (int mt = 0; mt < 2; ++mt)
#pragma unroll
              for (int hh = 0; hh < 2; ++hh)
#pragma unroll
                for (int e = 0; e < 4; ++e)
                  m |= (((u32)xm[j][mt][hh][e]) ^ expP) & 0x00010000u;
          if (__all((int)(m == 0u))) break;
          ++pit;
          if (pit > 16) __builtin_amdgcn_s_sleep(1);
          if ((pit & 255) == 0) {
            if (__hip_atomic_load(abortf, __ATOMIC_RELAXED, __HIP_MEMORY_SCOPE_AGENT)) { sdead = 1; break; }
            if (pit > (1 << 20)) {
              __hip_atomic_store(abortf, 1, __ATOMIC_RELAXED, __HIP_MEMORY_SCOPE_AGENT);
              sdead = 1; break;
            }
          }
        }
      }
#pragma unroll
      for (int j = 0; j < 4; ++j)
#pragma unroll
        for (int mt = 0; mt < 2; ++mt) {
          i32x4 w0 = xm[j][mt][0], w1 = xm[j][mt][1];
          i32x4 hi4;
          hi4[0] = (int)(((u32)w0[0] & 0xFFFFu) | ((u32)w0[1] << 16));
          hi4[1] = (int)(((u32)w0[2] & 0xFFFFu) | ((u32)w0[3] << 16));
          hi4[2] = (int)(((u32)w1[0] & 0xFFFFu) | ((u32)w1[1] << 16));
          hi4[3] = (int)(((u32)w1[2] & 0xFFFFu) | ((u32)w1[3] << 16));
          bf16x8 ax = __builtin_bit_cast(bf16x8, hi4);
#pragma unroll
          for (int nt = 0; nt < 2; ++nt)
            acc[mt][nt] = __builtin_amdgcn_mfma_f32_16x16x32_bf16(ax, BWi[j][nt], acc[mt][nt], 0, 0, 0);
        }
    }
    __syncthreads();                       // barrier B (gates h loads on q0's poll)
    if (sdead) return;

    // ---- h phase: packed-word loads, split-precision 3-term MFMAs ----
    const unsigned char* hs = PLP(g, (s + 15) & 15);
    i32x4 hw[4][2][2];
#pragma unroll
    for (int j = 0; j < 4; ++j)
#pragma unroll
      for (int mt = 0; mt < 2; ++mt) {
        LD16(hw[j][mt][0], hs + ao[j][mt]);
        LD16(hw[j][mt][1], hs + ao[j][mt] + 16);
      }
    WAIT0();
#pragma unroll
    for (int j = 0; j < 4; ++j)
#pragma unroll
      for (int mt = 0; mt < 2; ++mt) {
        i32x4 w0 = hw[j][mt][0], w1 = hw[j][mt][1];
        i32x4 hi4, lo4;
        hi4[0] = (int)(((u32)w0[0] & 0xFFFFu) | ((u32)w0[1] << 16));
        hi4[1] = (int)(((u32)w0[2] & 0xFFFFu) | ((u32)w0[3] << 16));
        hi4[2] = (int)(((u32)w1[0] & 0xFFFFu) | ((u32)w1[1] << 16));
        hi4[3] = (int)(((u32)w1[2] & 0xFFFFu) | ((u32)w1[3] << 16));
        lo4[0] = (int)(((u32)w0[0] >> 16) | ((u32)w0[1] & 0xFFFF0000u));
        lo4[1] = (int)(((u32)w0[2] >> 16) | ((u32)w0[3] & 0xFFFF0000u));
        lo4[2] = (int)(((u32)w1[0] >> 16) | ((u32)w1[1] & 0xFFFF0000u));
        lo4[3] = (int)(((u32)w1[2] >> 16) | ((u32)w1[3] & 0xFFFF0000u));
        bf16x8 ahi = __builtin_bit_cast(bf16x8, hi4);
        bf16x8 alo = __builtin_bit_cast(bf16x8, lo4);
#pragma unroll
        for (int nt = 0; nt < 2; ++nt) {
          acc[mt][nt] = __builtin_amdgcn_mfma_f32_16x16x32_bf16(ahi, BWh[j][nt],  acc[mt][nt], 0, 0, 0);
          acc[mt][nt] = __builtin_amdgcn_mfma_f32_16x16x32_bf16(alo, BWh[j][nt],  acc[mt][nt], 0, 0, 0);
          acc[mt][nt] = __builtin_amdgcn_mfma_f32_16x16x32_bf16(ahi, BWlo[j][nt], acc[mt][nt], 0, 0, 0);
        }
      }

    // ---- cross-wave K reduction via LDS ----
#pragma unroll
    for (int mt = 0; mt < 2; ++mt)
#pragma unroll
      for (int nt = 0; nt < 2; ++nt)
#pragma unroll
        for (int r = 0; r < 4; ++r)
          gb[q][mt*16 + (lane>>4)*4 + r][nt*16 + lrow] = acc[mt][nt][r];
    __syncthreads();                       // barrier C

    float gi = bgi, gf = bgf, gg2 = bgg, go = bgo;
#pragma unroll
    for (int qq = 0; qq < 4; ++qq) {
      gi  += gb[qq][bthr][uthr*4 + 0];
      gf  += gb[qq][bthr][uthr*4 + 1];
      gg2 += gb[qq][bthr][uthr*4 + 2];
      go  += gb[qq][bthr][uthr*4 + 3];
    }
    float si = 1.f/(1.f + __expf(-gi));
    float sf = 1.f/(1.f + __expf(-gf));
    float so = 1.f/(1.f + __expf(-go));
    cst = sf*cst + si*tanhf(gg2);
    float h = so*tanhf(cst);

    bf16 hhv = (bf16)h;
    bf16 hlv = (bf16)(h - (float)hhv);
    u16 lob = (u16)((__builtin_bit_cast(u16, hlv) & 0xFFFEu) | (u16)par_w);
    u32 word = (u32)__builtin_bit_cast(u16, hhv) | ((u32)lob << 16);
    ST4(PLP(g, slot_w) + (size_t)(bthr*512 + hu)*4, word);
    if (l == 1)
      H1p[((size_t)(s+1)*BB + bthr)*HH + hu] = hhv;          // plain store, read post-kernel

    WAIT0();                               // drain exchange stores
    __syncthreads();                       // barrier D: all waves drained
    if (tid == 0)
      __hip_atomic_store(flagw + (size_t)(g*1024 + s)*64 + w, 1,
                         __ATOMIC_RELAXED, __HIP_MEMORY_SCOPE_AGENT);
  }
}

#define SWZG(row, bc) ((u32)(row)*128u + ((u32)(bc) ^ ((((u32)(row))&7u)<<4)))

__launch_bounds__(256, 2)
__global__ void k_out(const unsigned char* __restrict__ ws,
                      const float* __restrict__ bout,
                      float* __restrict__ out) {
  __shared__ unsigned char As[64*128];
  __shared__ unsigned char Bs[128*128];
  const bf16* Hf = (const bf16*)(ws + OFF_H1);
  const bf16* Hb = Hf + H1_ELEM;
  const bf16* wbt = (const bf16*)(ws + OFF_WBT);

  const int m0 = blockIdx.x * 64;
  const int j0 = blockIdx.y * 128;
  const int tid = threadIdx.x, lane = tid & 63, q = tid >> 6;
  const int b = m0 >> 10;
  const int t0 = m0 & 1023;

  f32x4 acc[2][4];
#pragma unroll
  for (int mi = 0; mi < 2; ++mi)
#pragma unroll
    for (int ni = 0; ni < 4; ++ni) acc[mi][ni] = (f32x4){0.f,0.f,0.f,0.f};

  for (int kb = 0; kb < 16; ++kb) {
#pragma unroll
    for (int it = 0; it < 2; ++it) {
      int row = tid >> 2;
      int chunk = (tid & 3) + it*4;
      int k0 = kb*64 + chunk*8;
      int t = t0 + row;
      const bf16* src = (k0 < 512)
        ? (Hf + ((size_t)(t+1)*BB + b)*HH + k0)
        : (Hb + ((size_t)(TT - t)*BB + b)*HH + (k0 - 512));
      bf16x8 v = *(const bf16x8*)src;
#pragma unroll
      for (int e = 0; e < 8; ++e) { if ((float)v[e] < 0.f) v[e] = (bf16)0.f; }
      *(bf16x8*)(As + SWZG(row, chunk*16)) = v;
    }
#pragma unroll
    for (int it = 0; it < 4; ++it) {
      int j = (tid >> 3) + it*32;
      int chunk = tid & 7;
      int k0 = kb*64 + chunk*8;
      bf16x8 v = *(const bf16x8*)(wbt + (size_t)(j0+j)*1024 + k0);
      *(bf16x8*)(Bs + SWZG(j, chunk*16)) = v;
    }
    __syncthreads();
    const int mrow = (q & 1)*32;
    const int nc0 = (q >> 1)*64;
#pragma unroll
    for (int ks = 0; ks < 2; ++ks) {
      u32 koff = (u32)(ks*32 + (lane>>4)*8) * 2u;
      bf16x8 afr[2];
#pragma unroll
      for (int mi = 0; mi < 2; ++mi)
        afr[mi] = *(const bf16x8*)(As + SWZG(mrow + mi*16 + (lane&15), koff));
#pragma unroll
      for (int ni = 0; ni < 4; ++ni) {
        bf16x8 bfr = *(const bf16x8*)(Bs + SWZG(nc0 + ni*16 + (lane&15), koff));
#pragma unroll
        for (int mi = 0; mi < 2; ++mi)
          acc[mi][ni] = __builtin_amdgcn_mfma_f32_16x16x32_bf16(afr[mi], bfr, acc[mi][ni], 0, 0, 0);
      }
    }
    __syncthreads();
  }
#pragma unroll
  for (int ni = 0; ni < 4; ++ni) {
    int col = j0 + (q >> 1)*64 + ni*16 + (lane & 15);
    float bv = bout[col];
#pragma unroll
    for (int mi = 0; mi < 2; ++mi) {
#pragma unroll
      for (int r = 0; r < 4; ++r) {
        int m = m0 + (q & 1)*32 + mi*16 + (lane >> 4)*4 + r;
        out[(size_t)m*1024 + col] = acc[mi][ni][r] + bv;
      }
    }
  }
}

extern "C" void kernel_launch(void* const* d_in, const int* in_sizes, int n_in,
                              void* d_out, int out_size, void* d_ws, size_t ws_size,
                              hipStream_t stream) {
  const float* x    = (const float*)d_in[0];
  const float* h0   = (const float*)d_in[1];
  const float* c0   = (const float*)d_in[2];
  const float* Wi_f = (const float*)d_in[3];
  const float* Wh_f = (const float*)d_in[4];
  const float* b_f  = (const float*)d_in[5];
  const float* Wi_b = (const float*)d_in[6];
  const float* Wh_b = (const float*)d_in[7];
  const float* b_b  = (const float*)d_in[8];
  const float* Wo   = (const float*)d_in[9];
  const float* bo   = (const float*)d_in[10];
  unsigned char* ws = (unsigned char*)d_ws;
  float* out = (float*)d_out;

  hipLaunchKernelGGL(k_setup, dim3(2048), dim3(256), 0, stream,
                     h0, Wo, Wi_f, Wh_f, Wi_b, Wh_b, ws);

  void* args[] = { (void*)&x, (void*)&c0, (void*)&b_f, (void*)&b_b, (void*)&ws };
  hipError_t e = hipLaunchCooperativeKernel((const void*)k_rnn, dim3(256), dim3(256),
                                            args, 0, stream);
  if (e != hipSuccess) {
    // 256 blocks x 256 threads (1/CU) are co-resident under a normal launch too
    hipLaunchKernelGGL(k_rnn, dim3(256), dim3(256), 0, stream, x, c0, b_f, b_b, ws);
  }

  hipLaunchKernelGGL(k_out, dim3(512, 8), dim3(256), 0, stream,
                     (const unsigned char*)ws, bo, out);
}